// Round 5
// baseline (166.567 us; speedup 1.0000x reference)
//
#include <hip/hip_runtime.h>
#include <math.h>

// Problem constants
#define Bn 32
#define Sn 16384
#define Kn 64
#define Nn 128

#define P1  16           // pass-1 sample-chunks per (b,view)  (1024 blocks, 4/CU)
#define NSB 32           // pass-2 blocks per batch
#define SPB (Sn/NSB)     // 512 samples per gram block
#define NCH (SPB/32)     // 16 K-chunks of 32 samples

typedef __attribute__((ext_vector_type(8))) short bf16x8;   // 8 bf16 (4 VGPR)
typedef __attribute__((ext_vector_type(4))) float f32x4;    // MFMA acc

// workspace layout in floats
#define WS_CSPART 0                          // Bn*2*P1*64 = 65536
#define WS_GRAM   (Bn*2*P1*64)               // Bn*3*4096 final gram
#define WS_LOSS   (WS_GRAM + Bn*3*4096)      // Bn
#define WS_PART   (WS_LOSS + Bn)             // Bn*NSB*3*4096 partials
#define WS_PART_SZ ((size_t)Bn*NSB*3*4096)

__device__ __forceinline__ unsigned short f2bf(float f) {
    // round-to-nearest-even f32 -> bf16 (values are finite, no NaN handling)
    unsigned int u = __float_as_uint(f);
    u += 0x7FFFu + ((u >> 16) & 1u);
    return (unsigned short)(u >> 16);
}

// ---------------- Pass 1: column-sum partials ----------------
// Each thread bursts 16 float4 loads, sched_barrier(0) pins all 16 live
// (forces ~64 VGPR of in-flight data -> real MLP), then consumes.
// Blocks of one (b,view) stripe 4KB frames: frame = chunk + s*P1, so
// co-running blocks touch adjacent DRAM frames (copy-bench access pattern).
__global__ __launch_bounds__(256) void k_colsum(const float* __restrict__ qi,
                                                const float* __restrict__ qj,
                                                float* __restrict__ ws) {
    const int blk   = blockIdx.x;       // 0 .. Bn*2*P1-1
    const int chunk = blk % P1;
    const int pair  = blk / P1;         // b*2 + v
    const int v = pair & 1, b = pair >> 1;
    const float* __restrict__ src = v ? qj : qi;
    const int tid = threadIdx.x;
    const int c4 = (tid & 15) * 4;
    const int sg = tid >> 4;            // 0..15 (row within 16-row frame)
    // frame f covers rows f*16 .. f*16+15; this block owns f = chunk + s*P1
    const float* __restrict__ p0 =
        src + (long)b * Sn * Kn + (long)(chunk * 16 + sg) * Kn + c4;
    const long step = (long)P1 * 16 * Kn;   // address step per s

    float4 acc = make_float4(0.f, 0.f, 0.f, 0.f);
    // 64 frames per block, in 4 bursts of 16 in-flight loads
    #pragma unroll 1
    for (int g = 0; g < 4; ++g) {
        float4 vv[16];
        #pragma unroll
        for (int u = 0; u < 16; ++u)
            vv[u] = *(const float4*)(p0 + (long)(g * 16 + u) * step);
        __builtin_amdgcn_sched_barrier(0);   // all 16 loads issued before any use
        #pragma unroll
        for (int u = 0; u < 16; ++u) {
            acc.x += vv[u].x; acc.y += vv[u].y;
            acc.z += vv[u].z; acc.w += vv[u].w;
        }
    }
    __shared__ float red[16 * 64];
    *(float4*)&red[sg * 64 + c4] = acc;
    __syncthreads();
    if (tid < 64) {
        float s = 0.f;
        #pragma unroll
        for (int g = 0; g < 16; ++g) s += red[g * 64 + tid];
        ws[WS_CSPART + (pair * P1 + chunk) * 64 + tid] = s;
    }
}

// ---------------- Pass 2: normalize -> bf16 -> MFMA Gram (pipelined) ----------------
// Prologue folds the colsum-partial reduction.
// LDS: [buf][view] p^T chunk as [64 cols][40 bf16] (stride 80 B, 32 samples used).
// Frag (mfma_f32_16x16x32_bf16 A and B): lane l holds col = tile*16 + (l&15),
// samples (l>>4)*8 .. +7  ->  one 16B ds_read_b128 per fragment.
template<int ATOMIC>
__global__ __launch_bounds__(256, 4) void k_gram(const float* __restrict__ qi,
                                                 const float* __restrict__ qj,
                                                 float* __restrict__ ws) {
    const int b   = blockIdx.x / NSB;
    const int sb  = blockIdx.x % NSB;
    const int tid = threadIdx.x;
    const int w   = tid >> 6;        // wave 0..3 (owns output rows w*16..+15)
    const int l   = tid & 63;
    const int lc  = tid & 15;        // fragment col lane
    const int sp  = tid >> 4;        // sample-pair 0..15
    const int c0  = lc * 4;

    __shared__ unsigned short lp[2][2][64 * 40];   // [buf][view], 20.5 KB
    __shared__ float csh[128];                     // colsums: [view][64]

    // ---- fold: reduce colsum partials for this batch ----
    if (tid < 128) {
        const int view = tid >> 6, col = tid & 63;
        float s = 0.f;
        #pragma unroll
        for (int p = 0; p < P1; ++p)
            s += ws[WS_CSPART + ((b * 2 + view) * P1 + p) * 64 + col];
        csh[view * 64 + col] = s;
    }
    __syncthreads();

    const float icI[4] = {1.f / csh[c0], 1.f / csh[c0 + 1],
                          1.f / csh[c0 + 2], 1.f / csh[c0 + 3]};
    const float icJ[4] = {1.f / csh[64 + c0], 1.f / csh[64 + c0 + 1],
                          1.f / csh[64 + c0 + 2], 1.f / csh[64 + c0 + 3]};

    f32x4 aII[4], aIJ[4], aJJ[4];
    #pragma unroll
    for (int t = 0; t < 4; ++t) {
        aII[t] = (f32x4){0.f, 0.f, 0.f, 0.f};
        aIJ[t] = (f32x4){0.f, 0.f, 0.f, 0.f};
        aJJ[t] = (f32x4){0.f, 0.f, 0.f, 0.f};
    }

    const long bb  = (long)b * Sn * Kn;
    const long s0g = (long)sb * SPB;

    float4 pfa[2], pfb[2];   // prefetched chunk: [view] rows 2sp, 2sp+1

    auto issue = [&](int ct) {
        const long off = bb + (s0g + ct * 32 + 2 * sp) * (long)Kn + c0;
        pfa[0] = *(const float4*)(qi + off);
        pfb[0] = *(const float4*)(qi + off + Kn);
        pfa[1] = *(const float4*)(qj + off);
        pfb[1] = *(const float4*)(qj + off + Kn);
    };
    auto stage = [&](int buf) {
        #pragma unroll
        for (int v = 0; v < 2; ++v) {
            const float* ic = v ? icJ : icI;
            const float4 qa = pfa[v], qb = pfb[v];
            float wa[4] = {qa.x * qa.x * ic[0], qa.y * qa.y * ic[1],
                           qa.z * qa.z * ic[2], qa.w * qa.w * ic[3]};
            float wb[4] = {qb.x * qb.x * ic[0], qb.y * qb.y * ic[1],
                           qb.z * qb.z * ic[2], qb.w * qb.w * ic[3]};
            float ra = wa[0] + wa[1] + wa[2] + wa[3];
            float rb = wb[0] + wb[1] + wb[2] + wb[3];
            #pragma unroll
            for (int d = 1; d < 16; d <<= 1) {
                ra += __shfl_xor(ra, d);
                rb += __shfl_xor(rb, d);
            }
            const float ia = 1.f / ra, ib = 1.f / rb;
            #pragma unroll
            for (int cc = 0; cc < 4; ++cc) {
                const unsigned int pk = (unsigned int)f2bf(wa[cc] * ia)
                                      | ((unsigned int)f2bf(wb[cc] * ib) << 16);
                *(unsigned int*)&lp[buf][v][(c0 + cc) * 40 + 2 * sp] = pk;
            }
        }
    };

    // prologue
    issue(0);
    stage(0);
    issue(1);
    __syncthreads();

    const int sgo = (l >> 4) * 8;
    for (int ct = 0; ct < NCH; ++ct) {
        const int cur = ct & 1;
        const bf16x8 ai = *(const bf16x8*)&lp[cur][0][(w * 16 + lc) * 40 + sgo];
        const bf16x8 aj = *(const bf16x8*)&lp[cur][1][(w * 16 + lc) * 40 + sgo];
        #pragma unroll
        for (int nt = 0; nt < 4; ++nt) {
            const bf16x8 fi = *(const bf16x8*)&lp[cur][0][(nt * 16 + lc) * 40 + sgo];
            const bf16x8 fj = *(const bf16x8*)&lp[cur][1][(nt * 16 + lc) * 40 + sgo];
            aII[nt] = __builtin_amdgcn_mfma_f32_16x16x32_bf16(ai, fi, aII[nt], 0, 0, 0);
            aIJ[nt] = __builtin_amdgcn_mfma_f32_16x16x32_bf16(ai, fj, aIJ[nt], 0, 0, 0);
            aJJ[nt] = __builtin_amdgcn_mfma_f32_16x16x32_bf16(aj, fj, aJJ[nt], 0, 0, 0);
        }
        if (ct + 1 < NCH) {
            stage(cur ^ 1);                       // waits chunk ct+1 loads, fills other buf
            if (ct + 2 < NCH) issue(ct + 2);      // in flight across sync + next MFMA
        }
        __syncthreads();
    }

    // ---- epilogue: C/D layout col = l&15, row = (l>>4)*4 + reg ----
    const int row0 = w * 16 + (l >> 4) * 4;
    if (ATOMIC) {
        float* __restrict__ dst = ws + WS_GRAM + (long)b * 3 * 4096;
        #pragma unroll
        for (int nt = 0; nt < 4; ++nt) {
            #pragma unroll
            for (int r = 0; r < 4; ++r) {
                const int e = (row0 + r) * 64 + nt * 16 + lc;
                atomicAdd(&dst[e],        aII[nt][r]);
                atomicAdd(&dst[4096 + e], aIJ[nt][r]);
                atomicAdd(&dst[8192 + e], aJJ[nt][r]);
            }
        }
    } else {
        float* __restrict__ dst = ws + WS_PART + (long)(b * NSB + sb) * 3 * 4096;
        #pragma unroll
        for (int nt = 0; nt < 4; ++nt) {
            #pragma unroll
            for (int r = 0; r < 4; ++r) {
                const int e = (row0 + r) * 64 + nt * 16 + lc;
                dst[e]        = aII[nt][r];
                dst[4096 + e] = aIJ[nt][r];
                dst[8192 + e] = aJJ[nt][r];
            }
        }
    }
}

// ---------------- Pass 2b: reduce block partials (deterministic) ----------------
__global__ __launch_bounds__(256) void k_gram_reduce(float* __restrict__ ws) {
    const int idx = blockIdx.x * 256 + threadIdx.x;   // < Bn*3*4096
    const int b = idx / (3 * 4096);
    const int e = idx % (3 * 4096);
    float s = 0.f;
    #pragma unroll 8
    for (int p = 0; p < NSB; ++p)
        s += ws[WS_PART + (long)(b * NSB + p) * 3 * 4096 + e];
    ws[WS_GRAM + (long)b * 3 * 4096 + e] = s;
}

// ---------------- Pass 3: per-batch masked-LSE loss ----------------
__device__ __forceinline__ float sim_entry(const float* __restrict__ g, int r, int c) {
    // sim = [[Gii, Gij], [Gij^T, Gjj]]
    if (r < 64) return (c < 64) ? g[r * 64 + c] : g[4096 + r * 64 + (c - 64)];
    return (c < 64) ? g[4096 + c * 64 + (r - 64)] : g[8192 + (r - 64) * 64 + (c - 64)];
}

__global__ __launch_bounds__(128) void k_loss(const float* __restrict__ temp,
                                              float* __restrict__ ws) {
    const int b = blockIdx.x;
    const int r = threadIdx.x;    // row 0..127
    const float* __restrict__ g = ws + WS_GRAM + (long)b * 3 * 4096;
    const float inv_t = 1.f / temp[0];
    const int p = r ^ 64;         // positive-pair column

    float m = -1e30f, pos = 0.f;
    for (int c = 0; c < Nn; ++c) {
        if (c == r) continue;
        const float v = sim_entry(g, r, c) * inv_t;
        m = fmaxf(m, v);
        if (c == p) pos = v;
    }
    float sum = 0.f;
    for (int c = 0; c < Nn; ++c) {
        if (c == r) continue;
        const float v = sim_entry(g, r, c) * inv_t;
        sum += expf(v - m);
    }
    const float val = m + logf(sum) - pos;   // LSE - pos

    __shared__ float red[Nn];
    red[r] = val;
    __syncthreads();
    for (int st = 64; st > 0; st >>= 1) {
        if (r < st) red[r] += red[r + st];
        __syncthreads();
    }
    if (r == 0) ws[WS_LOSS + b] = red[0] / (float)Nn;
}

__global__ void k_final(float* __restrict__ ws, float* __restrict__ out) {
    if (threadIdx.x == 0) {
        float s = 0.f;
        for (int b = 0; b < Bn; ++b) s += ws[WS_LOSS + b];
        out[0] = s / (float)Bn;
    }
}

extern "C" void kernel_launch(void* const* d_in, const int* in_sizes, int n_in,
                              void* d_out, int out_size, void* d_ws, size_t ws_size,
                              hipStream_t stream) {
    const float* qi   = (const float*)d_in[0];
    const float* qj   = (const float*)d_in[1];
    const float* temp = (const float*)d_in[2];
    float* ws  = (float*)d_ws;
    float* out = (float*)d_out;

    const size_t need_f = (size_t)WS_PART + WS_PART_SZ;
    const bool partial = ws_size >= need_f * sizeof(float);

    k_colsum<<<Bn * 2 * P1, 256, 0, stream>>>(qi, qj, ws);

    if (partial) {
        k_gram<0><<<Bn * NSB, 256, 0, stream>>>(qi, qj, ws);
        k_gram_reduce<<<(Bn * 3 * 4096) / 256, 256, 0, stream>>>(ws);
    } else {
        hipMemsetAsync(ws + WS_GRAM, 0, (size_t)Bn * 3 * 4096 * sizeof(float), stream);
        k_gram<1><<<Bn * NSB, 256, 0, stream>>>(qi, qj, ws);
    }

    k_loss<<<Bn, 128, 0, stream>>>(temp, ws);
    k_final<<<1, 64, 0, stream>>>(ws, out);
}

// Round 6
// 163.470 us; speedup vs baseline: 1.0189x; 1.0189x over previous
//
#include <hip/hip_runtime.h>
#include <math.h>

// Problem constants
#define Bn 32
#define Sn 16384
#define Kn 64
#define Nn 128

#define P1  16           // pass-1 chunks per (b,view) -> 1024 blocks, 4/CU
#define NSB 32           // pass-2 blocks per batch
#define SPB (Sn/NSB)     // 512 samples per gram block
#define NCH (SPB/32)     // 16 K-chunks of 32 samples

typedef __attribute__((ext_vector_type(8))) short bf16x8;   // 8 bf16 (4 VGPR)
typedef __attribute__((ext_vector_type(4))) float f32x4;    // MFMA acc / load quad

// workspace layout in floats
#define WS_CSPART 0                          // Bn*2*P1*64 = 65536
#define WS_GRAM   (Bn*2*P1*64)               // Bn*3*4096 final gram
#define WS_LOSS   (WS_GRAM + Bn*3*4096)      // Bn
#define WS_PART   (WS_LOSS + Bn)             // Bn*NSB*3*4096 partials
#define WS_PART_SZ ((size_t)Bn*NSB*3*4096)

__device__ __forceinline__ unsigned short f2bf(float f) {
    // round-to-nearest-even f32 -> bf16 (values are finite, no NaN handling)
    unsigned int u = __float_as_uint(f);
    u += 0x7FFFu + ((u >> 16) & 1u);
    return (unsigned short)(u >> 16);
}

// ---------------- Pass 1: column-sum partials (inline-asm burst loads) ----------------
// Thread (rg, cp): rows rg*16..+15 of each 256-row block-iteration, cols cp*4..+3.
// 16 global_load_dwordx4 from ONE base reg with offset:k*256 (row stride 256 B).
// asm volatile => loads issue back-to-back, 16 distinct "=v" quads stay live
// (64 VGPRs of in-flight data the compiler cannot collapse), then one
// vmcnt(0) + sched_barrier(0) before the adds.
__global__ __launch_bounds__(256) void k_colsum(const float* __restrict__ qi,
                                                const float* __restrict__ qj,
                                                float* __restrict__ ws) {
    const int blk   = blockIdx.x;       // 0 .. Bn*2*P1-1
    const int chunk = blk % P1;
    const int pair  = blk / P1;         // b*2 + v
    const int v = pair & 1, b = pair >> 1;
    const float* __restrict__ src = v ? qj : qi;
    const int tid = threadIdx.x;
    const int cp = tid & 15;            // col phase
    const int c4 = cp * 4;
    const int rg = tid >> 4;            // row group 0..15
    // block region: rows [chunk*1024, +1024); 4 iterations x 256 rows
    const float* __restrict__ base0 =
        src + (long)b * Sn * Kn + (long)(chunk * (Sn / P1)) * Kn + c4;

    f32x4 acc = {0.f, 0.f, 0.f, 0.f};

    #pragma unroll 1
    for (int it = 0; it < 4; ++it) {
        const float* bp = base0 + (long)(it * 256 + rg * 16) * Kn;
        f32x4 q0, q1, q2, q3, q4, q5, q6, q7, q8, q9, q10, q11, q12, q13, q14, q15;
#define LDQ(n, o) asm volatile("global_load_dwordx4 %0, %1, off offset:" #o \
                               : "=v"(q##n) : "v"(bp))
        asm volatile("global_load_dwordx4 %0, %1, off" : "=v"(q0) : "v"(bp));
        LDQ(1, 256);  LDQ(2, 512);   LDQ(3, 768);   LDQ(4, 1024);
        LDQ(5, 1280); LDQ(6, 1536);  LDQ(7, 1792);  LDQ(8, 2048);
        LDQ(9, 2304); LDQ(10, 2560); LDQ(11, 2816); LDQ(12, 3072);
        LDQ(13, 3328); LDQ(14, 3584); LDQ(15, 3840);
#undef LDQ
        asm volatile("s_waitcnt vmcnt(0)" ::: "memory");
        __builtin_amdgcn_sched_barrier(0);
        q0 += q1;  q2 += q3;   q4 += q5;   q6 += q7;
        q8 += q9;  q10 += q11; q12 += q13; q14 += q15;
        q0 += q2;  q4 += q6;   q8 += q10;  q12 += q14;
        q0 += q4;  q8 += q12;
        acc += q0 + q8;
    }

    __shared__ float red[16 * 64];
    *(f32x4*)&red[rg * 64 + c4] = acc;
    __syncthreads();
    if (tid < 64) {
        float s = 0.f;
        #pragma unroll
        for (int g = 0; g < 16; ++g) s += red[g * 64 + tid];
        ws[WS_CSPART + (pair * P1 + chunk) * 64 + tid] = s;
    }
}

// ---------------- Pass 2: normalize -> bf16 -> MFMA Gram (pipelined) ----------------
// Prologue folds the colsum-partial reduction.
// LDS: [buf][view] p^T chunk as [64 cols][40 bf16] (stride 80 B, 32 samples used).
// Frag (mfma_f32_16x16x32_bf16 A and B): lane l holds col = tile*16 + (l&15),
// samples (l>>4)*8 .. +7  ->  one 16B ds_read_b128 per fragment.
template<int ATOMIC>
__global__ __launch_bounds__(256, 4) void k_gram(const float* __restrict__ qi,
                                                 const float* __restrict__ qj,
                                                 float* __restrict__ ws) {
    const int b   = blockIdx.x / NSB;
    const int sb  = blockIdx.x % NSB;
    const int tid = threadIdx.x;
    const int w   = tid >> 6;        // wave 0..3 (owns output rows w*16..+15)
    const int l   = tid & 63;
    const int lc  = tid & 15;        // fragment col lane
    const int sp  = tid >> 4;        // sample-pair 0..15
    const int c0  = lc * 4;

    __shared__ unsigned short lp[2][2][64 * 40];   // [buf][view], 20.5 KB
    __shared__ float csh[128];                     // colsums: [view][64]

    // ---- fold: reduce colsum partials for this batch ----
    if (tid < 128) {
        const int view = tid >> 6, col = tid & 63;
        float s = 0.f;
        #pragma unroll
        for (int p = 0; p < P1; ++p)
            s += ws[WS_CSPART + ((b * 2 + view) * P1 + p) * 64 + col];
        csh[view * 64 + col] = s;
    }
    __syncthreads();

    const float icI[4] = {1.f / csh[c0], 1.f / csh[c0 + 1],
                          1.f / csh[c0 + 2], 1.f / csh[c0 + 3]};
    const float icJ[4] = {1.f / csh[64 + c0], 1.f / csh[64 + c0 + 1],
                          1.f / csh[64 + c0 + 2], 1.f / csh[64 + c0 + 3]};

    f32x4 aII[4], aIJ[4], aJJ[4];
    #pragma unroll
    for (int t = 0; t < 4; ++t) {
        aII[t] = (f32x4){0.f, 0.f, 0.f, 0.f};
        aIJ[t] = (f32x4){0.f, 0.f, 0.f, 0.f};
        aJJ[t] = (f32x4){0.f, 0.f, 0.f, 0.f};
    }

    const long bb  = (long)b * Sn * Kn;
    const long s0g = (long)sb * SPB;

    float4 pfa[2], pfb[2];   // prefetched chunk: [view] rows 2sp, 2sp+1

    auto issue = [&](int ct) {
        const long off = bb + (s0g + ct * 32 + 2 * sp) * (long)Kn + c0;
        pfa[0] = *(const float4*)(qi + off);
        pfb[0] = *(const float4*)(qi + off + Kn);
        pfa[1] = *(const float4*)(qj + off);
        pfb[1] = *(const float4*)(qj + off + Kn);
    };
    auto stage = [&](int buf) {
        #pragma unroll
        for (int v = 0; v < 2; ++v) {
            const float* ic = v ? icJ : icI;
            const float4 qa = pfa[v], qb = pfb[v];
            float wa[4] = {qa.x * qa.x * ic[0], qa.y * qa.y * ic[1],
                           qa.z * qa.z * ic[2], qa.w * qa.w * ic[3]};
            float wb[4] = {qb.x * qb.x * ic[0], qb.y * qb.y * ic[1],
                           qb.z * qb.z * ic[2], qb.w * qb.w * ic[3]};
            float ra = wa[0] + wa[1] + wa[2] + wa[3];
            float rb = wb[0] + wb[1] + wb[2] + wb[3];
            #pragma unroll
            for (int d = 1; d < 16; d <<= 1) {
                ra += __shfl_xor(ra, d);
                rb += __shfl_xor(rb, d);
            }
            const float ia = 1.f / ra, ib = 1.f / rb;
            #pragma unroll
            for (int cc = 0; cc < 4; ++cc) {
                const unsigned int pk = (unsigned int)f2bf(wa[cc] * ia)
                                      | ((unsigned int)f2bf(wb[cc] * ib) << 16);
                *(unsigned int*)&lp[buf][v][(c0 + cc) * 40 + 2 * sp] = pk;
            }
        }
    };

    // prologue
    issue(0);
    stage(0);
    issue(1);
    __syncthreads();

    const int sgo = (l >> 4) * 8;
    for (int ct = 0; ct < NCH; ++ct) {
        const int cur = ct & 1;
        const bf16x8 ai = *(const bf16x8*)&lp[cur][0][(w * 16 + lc) * 40 + sgo];
        const bf16x8 aj = *(const bf16x8*)&lp[cur][1][(w * 16 + lc) * 40 + sgo];
        #pragma unroll
        for (int nt = 0; nt < 4; ++nt) {
            const bf16x8 fi = *(const bf16x8*)&lp[cur][0][(nt * 16 + lc) * 40 + sgo];
            const bf16x8 fj = *(const bf16x8*)&lp[cur][1][(nt * 16 + lc) * 40 + sgo];
            aII[nt] = __builtin_amdgcn_mfma_f32_16x16x32_bf16(ai, fi, aII[nt], 0, 0, 0);
            aIJ[nt] = __builtin_amdgcn_mfma_f32_16x16x32_bf16(ai, fj, aIJ[nt], 0, 0, 0);
            aJJ[nt] = __builtin_amdgcn_mfma_f32_16x16x32_bf16(aj, fj, aJJ[nt], 0, 0, 0);
        }
        if (ct + 1 < NCH) {
            stage(cur ^ 1);                       // waits chunk ct+1 loads, fills other buf
            if (ct + 2 < NCH) issue(ct + 2);      // in flight across sync + next MFMA
        }
        __syncthreads();
    }

    // ---- epilogue: C/D layout col = l&15, row = (l>>4)*4 + reg ----
    const int row0 = w * 16 + (l >> 4) * 4;
    if (ATOMIC) {
        float* __restrict__ dst = ws + WS_GRAM + (long)b * 3 * 4096;
        #pragma unroll
        for (int nt = 0; nt < 4; ++nt) {
            #pragma unroll
            for (int r = 0; r < 4; ++r) {
                const int e = (row0 + r) * 64 + nt * 16 + lc;
                atomicAdd(&dst[e],        aII[nt][r]);
                atomicAdd(&dst[4096 + e], aIJ[nt][r]);
                atomicAdd(&dst[8192 + e], aJJ[nt][r]);
            }
        }
    } else {
        float* __restrict__ dst = ws + WS_PART + (long)(b * NSB + sb) * 3 * 4096;
        #pragma unroll
        for (int nt = 0; nt < 4; ++nt) {
            #pragma unroll
            for (int r = 0; r < 4; ++r) {
                const int e = (row0 + r) * 64 + nt * 16 + lc;
                dst[e]        = aII[nt][r];
                dst[4096 + e] = aIJ[nt][r];
                dst[8192 + e] = aJJ[nt][r];
            }
        }
    }
}

// ---------------- Pass 2b: reduce block partials (deterministic) ----------------
__global__ __launch_bounds__(256) void k_gram_reduce(float* __restrict__ ws) {
    const int idx = blockIdx.x * 256 + threadIdx.x;   // < Bn*3*4096
    const int b = idx / (3 * 4096);
    const int e = idx % (3 * 4096);
    float s = 0.f;
    #pragma unroll 8
    for (int p = 0; p < NSB; ++p)
        s += ws[WS_PART + (long)(b * NSB + p) * 3 * 4096 + e];
    ws[WS_GRAM + (long)b * 3 * 4096 + e] = s;
}

// ---------------- Pass 3: per-batch masked-LSE loss ----------------
__device__ __forceinline__ float sim_entry(const float* __restrict__ g, int r, int c) {
    // sim = [[Gii, Gij], [Gij^T, Gjj]]
    if (r < 64) return (c < 64) ? g[r * 64 + c] : g[4096 + r * 64 + (c - 64)];
    return (c < 64) ? g[4096 + c * 64 + (r - 64)] : g[8192 + (r - 64) * 64 + (c - 64)];
}

__global__ __launch_bounds__(128) void k_loss(const float* __restrict__ temp,
                                              float* __restrict__ ws) {
    const int b = blockIdx.x;
    const int r = threadIdx.x;    // row 0..127
    const float* __restrict__ g = ws + WS_GRAM + (long)b * 3 * 4096;
    const float inv_t = 1.f / temp[0];
    const int p = r ^ 64;         // positive-pair column

    float m = -1e30f, pos = 0.f;
    for (int c = 0; c < Nn; ++c) {
        if (c == r) continue;
        const float v = sim_entry(g, r, c) * inv_t;
        m = fmaxf(m, v);
        if (c == p) pos = v;
    }
    float sum = 0.f;
    for (int c = 0; c < Nn; ++c) {
        if (c == r) continue;
        const float v = sim_entry(g, r, c) * inv_t;
        sum += expf(v - m);
    }
    const float val = m + logf(sum) - pos;   // LSE - pos

    __shared__ float red[Nn];
    red[r] = val;
    __syncthreads();
    for (int st = 64; st > 0; st >>= 1) {
        if (r < st) red[r] += red[r + st];
        __syncthreads();
    }
    if (r == 0) ws[WS_LOSS + b] = red[0] / (float)Nn;
}

__global__ void k_final(float* __restrict__ ws, float* __restrict__ out) {
    if (threadIdx.x == 0) {
        float s = 0.f;
        for (int b = 0; b < Bn; ++b) s += ws[WS_LOSS + b];
        out[0] = s / (float)Bn;
    }
}

extern "C" void kernel_launch(void* const* d_in, const int* in_sizes, int n_in,
                              void* d_out, int out_size, void* d_ws, size_t ws_size,
                              hipStream_t stream) {
    const float* qi   = (const float*)d_in[0];
    const float* qj   = (const float*)d_in[1];
    const float* temp = (const float*)d_in[2];
    float* ws  = (float*)d_ws;
    float* out = (float*)d_out;

    const size_t need_f = (size_t)WS_PART + WS_PART_SZ;
    const bool partial = ws_size >= need_f * sizeof(float);

    k_colsum<<<Bn * 2 * P1, 256, 0, stream>>>(qi, qj, ws);

    if (partial) {
        k_gram<0><<<Bn * NSB, 256, 0, stream>>>(qi, qj, ws);
        k_gram_reduce<<<(Bn * 3 * 4096) / 256, 256, 0, stream>>>(ws);
    } else {
        hipMemsetAsync(ws + WS_GRAM, 0, (size_t)Bn * 3 * 4096 * sizeof(float), stream);
        k_gram<1><<<Bn * NSB, 256, 0, stream>>>(qi, qj, ws);
    }

    k_loss<<<Bn, 128, 0, stream>>>(temp, ws);
    k_final<<<1, 64, 0, stream>>>(ws, out);
}